// Round 5
// baseline (393.485 us; speedup 1.0000x reference)
//
#include <hip/hip_runtime.h>
#include <hip/hip_bf16.h>
#include <stdint.h>

#define S   384
#define CM  256
#define CH  32
#define CZ  128
#define BB  256     // MSA depth b = K of GEMM1
#define EPS 1e-5f

typedef __attribute__((ext_vector_type(8))) short bf16x8;   // 8 bf16 = 4 VGPRs
typedef __attribute__((ext_vector_type(4))) float f32x4;

// workspace layout (bytes)
#define OFF_QT    0u                       // [12288][256] bf16 = 6291456  (row = i*32+c, col = b)
#define OFF_KT    6291456u                 // [12288][256] bf16            (row = j*32+d, col = b)
#define OFF_WT    (OFF_KT + 6291456u)      // [64][256] bf16 = 32768       WT[c][t] = g_in[t]*W[t][c]
#define OFF_WOT   (OFF_WT + 32768u)        // [128][1024] bf16 = 262144    WoTp[e][d*32+c] = Wo[c*32+d][e]

__device__ __forceinline__ unsigned short f2bf(float x) {
  union { __hip_bfloat16 h; unsigned short u; } v;
  v.h = __float2bfloat16(x);
  return v.u;
}

// async global->LDS, 16B per lane. lds offset wave-uniform; HW scatters lane L to base + L*16.
__device__ __forceinline__ void gload_lds16(const void* g, char* smem, uint32_t lds_off_uniform) {
  uint32_t l32 = (uint32_t)(uintptr_t)(smem + lds_off_uniform);
  __builtin_amdgcn_global_load_lds(
      (const __attribute__((address_space(1))) uint32_t*)(uintptr_t)g,
      (__attribute__((address_space(3))) uint32_t*)(uintptr_t)l32,
      16, 0, 0);
}

// O_lds swizzle, shared by writer (GEMM1 epilogue) and reader (stage 2).
// blk>>3 term: varies per-lane on the write side (spreads banks within one ds_write),
// constant-per-instruction on the read side (blk = kk*4+quad, quad<=3 never crosses an 8-group).
__device__ __forceinline__ int olds_off(int ij, int blk) {
  int slot = (blk & ~7) | (((blk & 7) ^ ((blk >> 3) & 7) ^ (ij & 7)) & 7);
  return ij * 2048 + slot * 16;
}

// ---------------- K0: prep WT (q|k concat, transposed, g_in-folded) and WoTp ------------------------
__global__ void k0_prep(const float* __restrict__ Wq, const float* __restrict__ Wk,
                        const float* __restrict__ Wo, const float* __restrict__ gin,
                        unsigned short* __restrict__ WTg, unsigned short* __restrict__ WoTg) {
  int idx = blockIdx.x * 256 + threadIdx.x;
  if (idx < 64 * 256) {
    int c = idx >> 8, t = idx & 255;
    float v = (c < 32) ? Wq[t * 32 + c] : Wk[t * 32 + (c - 32)];
    WTg[c * 256 + t] = f2bf(v * gin[t]);   // rmsnorm gain folded into the projection weight
  }
  int j = idx - 64 * 256;
  if (j >= 0 && j < 128 * 1024) {
    int e = j >> 10, dc = j & 1023;       // dc = d*32 + c  (stage-2 k order)
    int c = dc & 31, d = dc >> 5;
    WoTg[e * 1024 + dc] = f2bf(Wo[(c * 32 + d) * 128 + e]);
  }
}

// ---------------- K2: single-pass rmsnorm+projection. Reads m ONCE. ---------------------------------
// Identity: q = scl[row] * (m_raw @ (g*Wq)) + bq  (per-row scl commutes with the GEMM).
// 64 rows/block (16 b x 4 i), 256 thr = 4 waves. Per thread: 1/4 row, coalesced interleaved float4
// loads; ss accumulated in fp32 during the same pass; raw bf16 packed into swizzled A-LDS.
// MFMA loop is barrier-free (A fully staged). Epilogue applies scl + bias.
__global__ __launch_bounds__(256, 2) void k2_proj(const float* __restrict__ m,
                                                  const unsigned short* __restrict__ WTg,
                                                  const float* __restrict__ bq,
                                                  const float* __restrict__ bk,
                                                  unsigned short* __restrict__ qT,
                                                  unsigned short* __restrict__ kT) {
  // LDS: A [64 rows][256 k] bf16 swz @0 (32KB) | WT [64][256] swz @32768 (32KB) | scl[64] f32 @65536.
  // Cbuf [64][72] bf16 (9KB) aliases A region after the MFMA loop.
  __shared__ char smem[65792] __attribute__((aligned(16)));
  const int tid = threadIdx.x;
  const int w = tid >> 6, lane = tid & 63;
  const int mlo = lane & 15, quad = lane >> 4;
  const int i0 = blockIdx.x * 4, b0 = blockIdx.y * 16;
  float* scl = (float*)(smem + 65536);

  // stage WT (32KB) via async DMA; overlaps the m pass below
  #pragma unroll
  for (int s = 0; s < 8; ++s) {
    int C0 = (w * 8 + s) * 2;
    int c = C0 + (lane >> 5);
    int j = lane & 31;
    int t8 = (j & ~7) | ((j & 7) ^ (c & 7));
    gload_lds16(WTg + c * 256 + t8 * 8, smem, 32768u + (uint32_t)C0 * 512u);
  }

  // single m pass: row = tid>>2 (0..63), part = tid&3. Interleaved: float4 at k = part*4 + j*16.
  // Per instr: 4-lane groups cover 64B contiguous, 16 rows at 1KB stride -> line-coalesced.
  {
    const int row = tid >> 2, part = tid & 3;
    const size_t grow = (size_t)((b0 + (row >> 2)) * S + i0 + (row & 3)) * CM;
    const float* pm = m + grow;
    float ss = 0.f;
    #pragma unroll
    for (int j = 0; j < 16; ++j) {
      int k = part * 4 + j * 16;
      float4 x = *(const float4*)(pm + k);
      ss += x.x * x.x + x.y * x.y + x.z * x.z + x.w * x.w;
      union { unsigned short h[4]; uint2 q; } pk;
      pk.h[0] = f2bf(x.x); pk.h[1] = f2bf(x.y); pk.h[2] = f2bf(x.z); pk.h[3] = f2bf(x.w);
      int blk = (k >> 3) ^ (row & 7);
      *(uint2*)(smem + row * 512 + blk * 16 + (k & 7) * 2) = pk.q;
    }
    ss += __shfl_xor(ss, 1, 64);
    ss += __shfl_xor(ss, 2, 64);
    if (part == 0) scl[row] = rsqrtf(ss * (1.f / 256.f) + EPS);
  }
  __syncthreads();   // A staged, WT DMA drained (vmcnt(0) at barrier), scl ready

  // MFMA: wave w owns rows [w*16, w*16+16); acc = 16 rows x 64 cols; barrier-free
  f32x4 acc[4];
  #pragma unroll
  for (int q = 0; q < 4; ++q) acc[q] = (f32x4)0.f;
  #pragma unroll
  for (int kb = 0; kb < 4; ++kb) {
    #pragma unroll
    for (int ks = 0; ks < 2; ++ks) {
      int k8 = ks * 4 + quad;
      int mm = w * 16 + mlo;
      bf16x8 af = *(const bf16x8*)(smem + mm * 512 + kb * 128 + ((k8 ^ (mm & 7)) * 16));
      #pragma unroll
      for (int fn = 0; fn < 4; ++fn) {
        int c = fn * 16 + mlo;
        int t8 = kb * 8 + k8;
        bf16x8 bfr = *(const bf16x8*)(smem + 32768 + c * 512 + (((t8 & ~7) | ((t8 & 7) ^ (c & 7))) * 16));
        acc[fn] = __builtin_amdgcn_mfma_f32_16x16x32_bf16(af, bfr, acc[fn], 0, 0, 0);
      }
    }
  }
  __syncthreads();                       // all A/WT reads done; Cbuf may alias A region

  // epilogue: *scl, +bias -> Cbuf [64][72]
  unsigned short* Cl = (unsigned short*)smem;
  {
    float sr[4];
    #pragma unroll
    for (int r = 0; r < 4; ++r) sr[r] = scl[w * 16 + quad * 4 + r];
    #pragma unroll
    for (int fn = 0; fn < 4; ++fn) {
      int cc = fn * 16 + mlo;
      float bias = (cc < 32) ? bq[cc] : bk[cc - 32];
      #pragma unroll
      for (int r = 0; r < 4; ++r) {
        int rr = w * 16 + quad * 4 + r;
        Cl[rr * 72 + cc] = f2bf(acc[fn][r] * sr[r] + bias);
      }
    }
  }
  __syncthreads();
  // transpose-gather: thread (il = tid>>6, cc = tid&63) writes 16 b's for output row (i0+il)*32+cc
  {
    int il = tid >> 6, cc = tid & 63;
    unsigned short* dst = (cc < 32) ? (qT + ((i0 + il) * 32 + cc) * BB + b0)
                                    : (kT + ((i0 + il) * 32 + (cc - 32)) * BB + b0);
    #pragma unroll
    for (int v = 0; v < 2; ++v) {
      union { unsigned short h[8]; int4 q; } u;
      #pragma unroll
      for (int x = 0; x < 8; ++x) u.h[x] = Cl[((v * 8 + x) * 4 + il) * 72 + cc];
      *(int4*)(dst + v * 8) = u.q;
    }
  }
}

// ---------------- K3: 256x128 O-tile GEMM -> @Wo + bo -> rmsnorm -> z -------------------------------
// UNCHANGED from the measured 220us version (round 3).
__global__ __launch_bounds__(512, 4) void k3_fused(const unsigned short* __restrict__ qT,
                                                   const unsigned short* __restrict__ kT,
                                                   const unsigned short* __restrict__ WoTp,
                                                   const float* __restrict__ bo,
                                                   const float* __restrict__ gout,
                                                   float* __restrict__ out) {
  __shared__ char smem[65536] __attribute__((aligned(16)));
  const int tid = threadIdx.x;
  const int w = tid >> 6, lane = tid & 63;
  const int wm = w & 3, wn = w >> 2;          // GEMM1 wave grid 4 (m) x 2 (n)
  const int mlo = lane & 15, quad = lane >> 4;

  const int bid = blockIdx.x;                 // 0..4607
  const int xcd = bid & 7, idx = bid >> 3;    // idx 0..575
  const int ti = idx / 12;                    // 0..47  (A-panel reused by 12 consecutive blocks)
  const int tj = xcd * 12 + (idx % 12);       // 0..95

  f32x4 acc[4][4];
  #pragma unroll
  for (int p = 0; p < 4; ++p)
    #pragma unroll
    for (int q = 0; q < 4; ++q) acc[p][q] = (f32x4)0.f;

  auto stageA = [&](int kb) {
    #pragma unroll
    for (int s = 0; s < 4; ++s) {
      int r = w * 32 + s * 8 + (lane >> 3);
      int k8 = (lane & 7) ^ (r & 7);
      gload_lds16(qT + (ti * 256 + r) * BB + kb * 64 + k8 * 8, smem, (uint32_t)(w * 32 + s * 8) * 128u);
    }
  };
  auto stageB = [&](int kb, int bsel) {
    #pragma unroll
    for (int s = 0; s < 2; ++s) {
      int r = w * 16 + s * 8 + (lane >> 3);
      int k8 = (lane & 7) ^ (r & 7);
      gload_lds16(kT + (tj * 128 + r) * BB + kb * 64 + k8 * 8, smem,
                  32768u + (uint32_t)bsel * 16384u + (uint32_t)(w * 16 + s * 8) * 128u);
    }
  };

  stageA(0); stageB(0, 0);
  __syncthreads();

  for (int kb = 0; kb < 4; ++kb) {
    const int bsel = kb & 1;
    bf16x8 afr[4], bfr[4];
    #pragma unroll
    for (int f = 0; f < 4; ++f) {
      int mm = wm * 64 + f * 16 + mlo;
      afr[f] = *(const bf16x8*)(smem + mm * 128 + ((quad ^ (mm & 7)) * 16));
    }
    #pragma unroll
    for (int f = 0; f < 4; ++f) {
      int nn = wn * 64 + f * 16 + mlo;
      bfr[f] = *(const bf16x8*)(smem + 32768 + bsel * 16384 + nn * 128 + ((quad ^ (nn & 7)) * 16));
    }
    #pragma unroll
    for (int fm = 0; fm < 4; ++fm)
      #pragma unroll
      for (int fn = 0; fn < 4; ++fn)
        acc[fm][fn] = __builtin_amdgcn_mfma_f32_16x16x32_bf16(afr[fm], bfr[fn], acc[fm][fn], 0, 0, 0);
    bf16x8 af1[4];
    #pragma unroll
    for (int f = 0; f < 4; ++f) {
      int mm = wm * 64 + f * 16 + mlo;
      af1[f] = *(const bf16x8*)(smem + mm * 128 + (((4 + quad) ^ (mm & 7)) * 16));
    }
    __syncthreads();
    if (kb < 3) { stageA(kb + 1); stageB(kb + 1, bsel ^ 1); }
    #pragma unroll
    for (int f = 0; f < 4; ++f) {
      int nn = wn * 64 + f * 16 + mlo;
      bfr[f] = *(const bf16x8*)(smem + 32768 + bsel * 16384 + nn * 128 + (((4 + quad) ^ (nn & 7)) * 16));
    }
    #pragma unroll
    for (int fm = 0; fm < 4; ++fm)
      #pragma unroll
      for (int fn = 0; fn < 4; ++fn)
        acc[fm][fn] = __builtin_amdgcn_mfma_f32_16x16x32_bf16(af1[fm], bfr[fn], acc[fm][fn], 0, 0, 0);
    __syncthreads();
  }

  #pragma unroll
  for (int fm = 0; fm < 4; ++fm)
    #pragma unroll
    for (int fn = 0; fn < 4; ++fn) {
      int col = wn * 64 + fn * 16 + mlo;
      int row0 = wm * 64 + fm * 16 + quad * 4;
      int ij = (row0 >> 5) * 4 + (col >> 5);
      int k20 = (col & 31) * 32 + (row0 & 31);
      int blk = k20 >> 3;
      int off = olds_off(ij, blk) + (k20 & 7) * 2;
      union { unsigned short h[4]; uint2 u; } pk;
      #pragma unroll
      for (int r = 0; r < 4; ++r) pk.h[r] = f2bf(acc[fm][fn][r]);
      *(uint2*)(smem + off) = pk.u;
    }
  __syncthreads();

  const int eg = w >> 1, kh = w & 1;
  const int e0 = eg * 32;
  f32x4 acc2[2][2];
  #pragma unroll
  for (int p = 0; p < 2; ++p)
    #pragma unroll
    for (int q = 0; q < 2; ++q) acc2[p][q] = (f32x4)0.f;

  #pragma unroll 4
  for (int s = 0; s < 16; ++s) {
    int kk = kh * 16 + s;
    int k = kk * 32 + quad * 8;
    int blk = kk * 4 + quad;
    bf16x8 b[2];
    #pragma unroll
    for (int fe = 0; fe < 2; ++fe)
      b[fe] = *(const bf16x8*)(WoTp + (size_t)(e0 + fe * 16 + mlo) * 1024 + k);
    #pragma unroll
    for (int fij = 0; fij < 2; ++fij) {
      int ij = fij * 16 + mlo;
      bf16x8 a = *(const bf16x8*)(smem + olds_off(ij, blk));
      #pragma unroll
      for (int fe = 0; fe < 2; ++fe)
        acc2[fij][fe] = __builtin_amdgcn_mfma_f32_16x16x32_bf16(a, b[fe], acc2[fij][fe], 0, 0, 0);
    }
  }
  __syncthreads();

  float* partf = (float*)smem;           // [4 eg][32 ij][33] f32
  float* red   = (float*)(smem + 16896); // [32 ij][4 eg]
  float* sclp  = (float*)(smem + 17408); // [32]
  if (kh == 1) {
    #pragma unroll
    for (int fij = 0; fij < 2; ++fij)
      #pragma unroll
      for (int fe = 0; fe < 2; ++fe)
        #pragma unroll
        for (int r = 0; r < 4; ++r)
          partf[eg * 1056 + (fij * 16 + quad * 4 + r) * 33 + fe * 16 + mlo] = acc2[fij][fe][r];
  }
  __syncthreads();

  float v[2][2][4];
  if (kh == 0) {
    float bv[2], gv[2];
    #pragma unroll
    for (int fe = 0; fe < 2; ++fe) { bv[fe] = bo[e0 + fe * 16 + mlo]; gv[fe] = gout[e0 + fe * 16 + mlo]; }
    float sq[2][4];
    #pragma unroll
    for (int fij = 0; fij < 2; ++fij)
      #pragma unroll
      for (int r = 0; r < 4; ++r) {
        float t = 0.f;
        #pragma unroll
        for (int fe = 0; fe < 2; ++fe) {
          float x = acc2[fij][fe][r] + partf[eg * 1056 + (fij * 16 + quad * 4 + r) * 33 + fe * 16 + mlo] + bv[fe];
          v[fij][fe][r] = x * gv[fe];
          t += x * x;
        }
        sq[fij][r] = t;
      }
    #pragma unroll
    for (int o = 1; o < 16; o <<= 1)
      #pragma unroll
      for (int fij = 0; fij < 2; ++fij)
        #pragma unroll
        for (int r = 0; r < 4; ++r) sq[fij][r] += __shfl_xor(sq[fij][r], o, 64);
    if (mlo == 0) {
      #pragma unroll
      for (int fij = 0; fij < 2; ++fij)
        #pragma unroll
        for (int r = 0; r < 4; ++r) red[(fij * 16 + quad * 4 + r) * 4 + eg] = sq[fij][r];
    }
  }
  __syncthreads();
  if (tid < 32) {
    float t = red[tid * 4] + red[tid * 4 + 1] + red[tid * 4 + 2] + red[tid * 4 + 3];
    sclp[tid] = rsqrtf(t * (1.f / 128.f) + EPS);
  }
  __syncthreads();
  if (kh == 0) {
    #pragma unroll
    for (int fij = 0; fij < 2; ++fij)
      #pragma unroll
      for (int r = 0; r < 4; ++r) {
        int ij = fij * 16 + quad * 4 + r;
        float sc = sclp[ij];
        int gi = ti * 8 + (ij >> 2), gj = tj * 4 + (ij & 3);
        #pragma unroll
        for (int fe = 0; fe < 2; ++fe)
          out[((size_t)gi * S + gj) * CZ + e0 + fe * 16 + mlo] = v[fij][fe][r] * sc;
      }
  }
}

// ---------------------------------------------------------------------------------------------------
extern "C" void kernel_launch(void* const* d_in, const int* in_sizes, int n_in,
                              void* d_out, int out_size, void* d_ws, size_t ws_size,
                              hipStream_t stream) {
  const float* m    = (const float*)d_in[0];
  const float* gin  = (const float*)d_in[1];
  const float* Wq   = (const float*)d_in[2];
  const float* bq   = (const float*)d_in[3];
  const float* Wk   = (const float*)d_in[4];
  const float* bk   = (const float*)d_in[5];
  const float* Wo   = (const float*)d_in[6];
  const float* bo   = (const float*)d_in[7];
  const float* gout = (const float*)d_in[8];

  char* ws = (char*)d_ws;
  unsigned short* qT    = (unsigned short*)(ws + OFF_QT);
  unsigned short* kT    = (unsigned short*)(ws + OFF_KT);
  unsigned short* WTg   = (unsigned short*)(ws + OFF_WT);
  unsigned short* WoTp  = (unsigned short*)(ws + OFF_WOT);
  float* out = (float*)d_out;

  hipLaunchKernelGGL(k0_prep, dim3(576), dim3(256), 0, stream, Wq, Wk, Wo, gin, WTg, WoTp);
  hipLaunchKernelGGL(k2_proj, dim3(96, 16), dim3(256), 0, stream, m, WTg, bq, bk, qT, kT);
  hipLaunchKernelGGL(k3_fused, dim3(4608), dim3(512), 0, stream, qT, kT, WoTp, bo, gout, out);
}

// Round 6
// 391.471 us; speedup vs baseline: 1.0051x; 1.0051x over previous
//
#include <hip/hip_runtime.h>
#include <hip/hip_bf16.h>
#include <stdint.h>

#define S   384
#define CM  256
#define CH  32
#define CZ  128
#define BB  256     // MSA depth b = K of GEMM1
#define EPS 1e-5f

typedef __attribute__((ext_vector_type(8))) short bf16x8;   // 8 bf16 = 4 VGPRs
typedef __attribute__((ext_vector_type(4))) float f32x4;

// workspace layout (bytes)
#define OFF_QT    0u                       // [12288][256] bf16 = 6291456  (row = i*32+c, col = b)
#define OFF_KT    6291456u                 // [12288][256] bf16            (row = j*32+d, col = b)
#define OFF_WT    (OFF_KT + 6291456u)      // [64][256] bf16 = 32768       WT[c][t] = g_in[t]*W[t][c]
#define OFF_WOT   (OFF_WT + 32768u)        // [128][1024] bf16 = 262144    WoTp[e][d*32+c] = Wo[c*32+d][e]

__device__ __forceinline__ unsigned short f2bf(float x) {
  union { __hip_bfloat16 h; unsigned short u; } v;
  v.h = __float2bfloat16(x);
  return v.u;
}

// async global->LDS, 16B per lane. lds offset wave-uniform; HW scatters lane L to base + L*16.
__device__ __forceinline__ void gload_lds16(const void* g, char* smem, uint32_t lds_off_uniform) {
  uint32_t l32 = (uint32_t)(uintptr_t)(smem + lds_off_uniform);
  __builtin_amdgcn_global_load_lds(
      (const __attribute__((address_space(1))) uint32_t*)(uintptr_t)g,
      (__attribute__((address_space(3))) uint32_t*)(uintptr_t)l32,
      16, 0, 0);
}

// O_lds swizzle, shared by writer (GEMM1 epilogue) and reader (stage 2).
__device__ __forceinline__ int olds_off(int ij, int blk) {
  int slot = (blk & ~7) | (((blk & 7) ^ ((blk >> 3) & 7) ^ (ij & 7)) & 7);
  return ij * 2048 + slot * 16;
}

// ---------------- K0: prep WT (q|k concat, transposed, g_in-folded) and WoTp ------------------------
__global__ void k0_prep(const float* __restrict__ Wq, const float* __restrict__ Wk,
                        const float* __restrict__ Wo, const float* __restrict__ gin,
                        unsigned short* __restrict__ WTg, unsigned short* __restrict__ WoTg) {
  int idx = blockIdx.x * 256 + threadIdx.x;
  if (idx < 64 * 256) {
    int c = idx >> 8, t = idx & 255;
    float v = (c < 32) ? Wq[t * 32 + c] : Wk[t * 32 + (c - 32)];
    WTg[c * 256 + t] = f2bf(v * gin[t]);   // rmsnorm gain folded into the projection weight
  }
  int j = idx - 64 * 256;
  if (j >= 0 && j < 128 * 1024) {
    int e = j >> 10, dc = j & 1023;       // dc = d*32 + c  (stage-2 k order)
    int c = dc & 31, d = dc >> 5;
    WoTg[e * 1024 + dc] = f2bf(Wo[(c * 32 + d) * 128 + e]);
  }
}

// ---------------- K2: single-pass rmsnorm+projection. Reads m ONCE. ---------------------------------
__global__ __launch_bounds__(256, 2) void k2_proj(const float* __restrict__ m,
                                                  const unsigned short* __restrict__ WTg,
                                                  const float* __restrict__ bq,
                                                  const float* __restrict__ bk,
                                                  unsigned short* __restrict__ qT,
                                                  unsigned short* __restrict__ kT) {
  // LDS: A [64 rows][256 k] bf16 swz @0 (32KB) | WT [64][256] swz @32768 (32KB) | scl[64] f32 @65536.
  __shared__ char smem[65792] __attribute__((aligned(16)));
  const int tid = threadIdx.x;
  const int w = tid >> 6, lane = tid & 63;
  const int mlo = lane & 15, quad = lane >> 4;
  const int i0 = blockIdx.x * 4, b0 = blockIdx.y * 16;
  float* scl = (float*)(smem + 65536);

  #pragma unroll
  for (int s = 0; s < 8; ++s) {
    int C0 = (w * 8 + s) * 2;
    int c = C0 + (lane >> 5);
    int j = lane & 31;
    int t8 = (j & ~7) | ((j & 7) ^ (c & 7));
    gload_lds16(WTg + c * 256 + t8 * 8, smem, 32768u + (uint32_t)C0 * 512u);
  }

  // single m pass: row = tid>>2 (0..63), part = tid&3; interleaved float4 loads, ss in fp32.
  {
    const int row = tid >> 2, part = tid & 3;
    const size_t grow = (size_t)((b0 + (row >> 2)) * S + i0 + (row & 3)) * CM;
    const float* pm = m + grow;
    float ss = 0.f;
    #pragma unroll
    for (int j = 0; j < 16; ++j) {
      int k = part * 4 + j * 16;
      float4 x = *(const float4*)(pm + k);
      ss += x.x * x.x + x.y * x.y + x.z * x.z + x.w * x.w;
      union { unsigned short h[4]; uint2 q; } pk;
      pk.h[0] = f2bf(x.x); pk.h[1] = f2bf(x.y); pk.h[2] = f2bf(x.z); pk.h[3] = f2bf(x.w);
      int blk = (k >> 3) ^ (row & 7);
      *(uint2*)(smem + row * 512 + blk * 16 + (k & 7) * 2) = pk.q;
    }
    ss += __shfl_xor(ss, 1, 64);
    ss += __shfl_xor(ss, 2, 64);
    if (part == 0) scl[row] = rsqrtf(ss * (1.f / 256.f) + EPS);
  }
  __syncthreads();   // A staged, WT DMA drained, scl ready

  f32x4 acc[4];
  #pragma unroll
  for (int q = 0; q < 4; ++q) acc[q] = (f32x4)0.f;
  #pragma unroll
  for (int kb = 0; kb < 4; ++kb) {
    #pragma unroll
    for (int ks = 0; ks < 2; ++ks) {
      int k8 = ks * 4 + quad;
      int mm = w * 16 + mlo;
      bf16x8 af = *(const bf16x8*)(smem + mm * 512 + kb * 128 + ((k8 ^ (mm & 7)) * 16));
      #pragma unroll
      for (int fn = 0; fn < 4; ++fn) {
        int c = fn * 16 + mlo;
        int t8 = kb * 8 + k8;
        bf16x8 bfr = *(const bf16x8*)(smem + 32768 + c * 512 + (((t8 & ~7) | ((t8 & 7) ^ (c & 7))) * 16));
        acc[fn] = __builtin_amdgcn_mfma_f32_16x16x32_bf16(af, bfr, acc[fn], 0, 0, 0);
      }
    }
  }
  __syncthreads();                       // all A/WT reads done; Cbuf may alias A region

  unsigned short* Cl = (unsigned short*)smem;
  {
    float sr[4];
    #pragma unroll
    for (int r = 0; r < 4; ++r) sr[r] = scl[w * 16 + quad * 4 + r];
    #pragma unroll
    for (int fn = 0; fn < 4; ++fn) {
      int cc = fn * 16 + mlo;
      float bias = (cc < 32) ? bq[cc] : bk[cc - 32];
      #pragma unroll
      for (int r = 0; r < 4; ++r) {
        int rr = w * 16 + quad * 4 + r;
        Cl[rr * 72 + cc] = f2bf(acc[fn][r] * sr[r] + bias);
      }
    }
  }
  __syncthreads();
  {
    int il = tid >> 6, cc = tid & 63;
    unsigned short* dst = (cc < 32) ? (qT + ((i0 + il) * 32 + cc) * BB + b0)
                                    : (kT + ((i0 + il) * 32 + (cc - 32)) * BB + b0);
    #pragma unroll
    for (int v = 0; v < 2; ++v) {
      union { unsigned short h[8]; int4 q; } u;
      #pragma unroll
      for (int x = 0; x < 8; ++x) u.h[x] = Cl[((v * 8 + x) * 4 + il) * 72 + cc];
      *(int4*)(dst + v * 8) = u.q;
    }
  }
}

// ---------------- K3: 256x128 O-tile GEMM -> @Wo + bo -> rmsnorm -> z -------------------------------
// GEMM1 rebuilt as proper T3/T4 pipeline: BK=32, A AND B double-buffered
// (A0@0, A1@16K each [256][32]; B0@32K, B1@40K each [128][32]; 48KB peak, O_lds 64KB aliases after).
// Per K-step: raw s_barrier -> issue next stage (3 DMA/wave) -> s_waitcnt vmcnt(3) COUNTED
// (next tile's loads stay in flight across the barrier; never drain to 0 in-loop) -> raw barrier ->
// 8 ds_read_b128 + 16 MFMA under setprio(1). Stage-2 adds depth-2 WoTp register prefetch.
__global__ __launch_bounds__(512, 4) void k3_fused(const unsigned short* __restrict__ qT,
                                                   const unsigned short* __restrict__ kT,
                                                   const unsigned short* __restrict__ WoTp,
                                                   const float* __restrict__ bo,
                                                   const float* __restrict__ gout,
                                                   float* __restrict__ out) {
  __shared__ char smem[65536] __attribute__((aligned(16)));
  const int tid = threadIdx.x;
  const int w = tid >> 6, lane = tid & 63;
  const int wm = w & 3, wn = w >> 2;          // GEMM1 wave grid 4 (m) x 2 (n)
  const int mlo = lane & 15, quad = lane >> 4;

  const int bid = blockIdx.x;                 // 0..4607
  const int xcd = bid & 7, idx = bid >> 3;    // idx 0..575
  const int ti = idx / 12;                    // 0..47
  const int tj = xcd * 12 + (idx % 12);       // 0..95

  f32x4 acc[4][4];
  #pragma unroll
  for (int p = 0; p < 4; ++p)
    #pragma unroll
    for (int q = 0; q < 4; ++q) acc[p][q] = (f32x4)0.f;

  // stage one BK=32 slice into buffer p: per wave 2 A-loads (32 rows) + 1 B-load (16 rows).
  // LDS rows are 64B (4 x 16B slots), slot-swizzled: LDS[r][s] holds global k-chunk g = s ^ ((r>>1)&3).
  auto stageAB = [&](int kb, int p) {
    uint32_t Ab = (uint32_t)p * 16384u;
    uint32_t Bb = 32768u + (uint32_t)p * 8192u;
    #pragma unroll
    for (int s = 0; s < 2; ++s) {
      int r = w * 32 + s * 16 + (lane >> 2);
      int g = (lane & 3) ^ ((r >> 1) & 3);
      gload_lds16(qT + (ti * 256 + r) * BB + kb * 32 + g * 8, smem, Ab + (uint32_t)(w * 32 + s * 16) * 64u);
    }
    {
      int r = w * 16 + (lane >> 2);
      int g = (lane & 3) ^ ((r >> 1) & 3);
      gload_lds16(kT + (tj * 128 + r) * BB + kb * 32 + g * 8, smem, Bb + (uint32_t)(w * 16) * 64u);
    }
  };

  stageAB(0, 0);                              // 3 loads in flight

  #pragma unroll
  for (int kb = 0; kb < 8; ++kb) {
    const int p = kb & 1;
    // barrier A: all waves consumed buf[p^1] frags (enforced by MFMA reg-dep last iter)
    __builtin_amdgcn_s_barrier();
    __builtin_amdgcn_sched_barrier(0);
    if (kb < 7) {
      stageAB(kb + 1, p ^ 1);                 // overwrite of p^1 is now safe
      asm volatile("s_waitcnt vmcnt(3)" ::: "memory");   // kb's 3 landed; kb+1's 3 stay in flight
    } else {
      asm volatile("s_waitcnt vmcnt(0)" ::: "memory");   // tail: drain last slice
    }
    __builtin_amdgcn_sched_barrier(0);
    // barrier B: every wave's kb loads landed -> buf[p] fully valid
    __builtin_amdgcn_s_barrier();
    __builtin_amdgcn_sched_barrier(0);
    bf16x8 afr[4], bfr[4];
    #pragma unroll
    for (int f = 0; f < 4; ++f) {
      int mm = wm * 64 + f * 16 + mlo;
      afr[f] = *(const bf16x8*)(smem + p * 16384 + mm * 64 + ((quad ^ ((mm >> 1) & 3)) * 16));
      int nn = wn * 64 + f * 16 + mlo;
      bfr[f] = *(const bf16x8*)(smem + 32768 + p * 8192 + nn * 64 + ((quad ^ ((nn >> 1) & 3)) * 16));
    }
    __builtin_amdgcn_s_setprio(1);
    #pragma unroll
    for (int fm = 0; fm < 4; ++fm)
      #pragma unroll
      for (int fn = 0; fn < 4; ++fn)
        acc[fm][fn] = __builtin_amdgcn_mfma_f32_16x16x32_bf16(afr[fm], bfr[fn], acc[fm][fn], 0, 0, 0);
    __builtin_amdgcn_s_setprio(0);
  }
  __syncthreads();   // GEMM1 done (DMA drained at kb=7); O_lds aliases the full 64KB

  // -------- O (C-layout regs) -> O_lds[ij][k2'] bf16, k2' = d*32 + c --------
  #pragma unroll
  for (int fm = 0; fm < 4; ++fm)
    #pragma unroll
    for (int fn = 0; fn < 4; ++fn) {
      int col = wn * 64 + fn * 16 + mlo;
      int row0 = wm * 64 + fm * 16 + quad * 4;
      int ij = (row0 >> 5) * 4 + (col >> 5);
      int k20 = (col & 31) * 32 + (row0 & 31);
      int blk = k20 >> 3;
      int off = olds_off(ij, blk) + (k20 & 7) * 2;
      union { unsigned short h[4]; uint2 u; } pk;
      #pragma unroll
      for (int r = 0; r < 4; ++r) pk.h[r] = f2bf(acc[fm][fn][r]);
      *(uint2*)(smem + off) = pk.u;
    }
  __syncthreads();

  // -------- stage 2: z[32 ij][128 e] = O @ Wo; wave (eg,kh); depth-2 WoTp reg prefetch --------
  const int eg = w >> 1, kh = w & 1;
  const int e0 = eg * 32;
  f32x4 acc2[2][2];
  #pragma unroll
  for (int p = 0; p < 2; ++p)
    #pragma unroll
    for (int q = 0; q < 2; ++q) acc2[p][q] = (f32x4)0.f;

  const unsigned short* wr0 = WoTp + (size_t)(e0 + mlo) * 1024;
  const unsigned short* wr1 = WoTp + (size_t)(e0 + 16 + mlo) * 1024;
  bf16x8 bc[2], bn[2];
  bc[0] = *(const bf16x8*)(wr0 + (kh * 16) * 32 + quad * 8);
  bc[1] = *(const bf16x8*)(wr1 + (kh * 16) * 32 + quad * 8);
  #pragma unroll
  for (int s = 0; s < 16; ++s) {
    int kk = kh * 16 + s;
    if (s < 15) {
      bn[0] = *(const bf16x8*)(wr0 + (kk + 1) * 32 + quad * 8);
      bn[1] = *(const bf16x8*)(wr1 + (kk + 1) * 32 + quad * 8);
    }
    int blk = kk * 4 + quad;
    __builtin_amdgcn_s_setprio(1);
    #pragma unroll
    for (int fij = 0; fij < 2; ++fij) {
      int ij = fij * 16 + mlo;
      bf16x8 a = *(const bf16x8*)(smem + olds_off(ij, blk));
      #pragma unroll
      for (int fe = 0; fe < 2; ++fe)
        acc2[fij][fe] = __builtin_amdgcn_mfma_f32_16x16x32_bf16(a, bc[fe], acc2[fij][fe], 0, 0, 0);
    }
    __builtin_amdgcn_s_setprio(0);
    bc[0] = bn[0]; bc[1] = bn[1];
  }
  __syncthreads();                       // all O_lds reads done; partials may alias smem

  float* partf = (float*)smem;           // [4 eg][32 ij][33] f32
  float* red   = (float*)(smem + 16896); // [32 ij][4 eg]
  float* sclp  = (float*)(smem + 17408); // [32]
  if (kh == 1) {
    #pragma unroll
    for (int fij = 0; fij < 2; ++fij)
      #pragma unroll
      for (int fe = 0; fe < 2; ++fe)
        #pragma unroll
        for (int r = 0; r < 4; ++r)
          partf[eg * 1056 + (fij * 16 + quad * 4 + r) * 33 + fe * 16 + mlo] = acc2[fij][fe][r];
  }
  __syncthreads();

  float v[2][2][4];
  if (kh == 0) {
    float bv[2], gv[2];
    #pragma unroll
    for (int fe = 0; fe < 2; ++fe) { bv[fe] = bo[e0 + fe * 16 + mlo]; gv[fe] = gout[e0 + fe * 16 + mlo]; }
    float sq[2][4];
    #pragma unroll
    for (int fij = 0; fij < 2; ++fij)
      #pragma unroll
      for (int r = 0; r < 4; ++r) {
        float t = 0.f;
        #pragma unroll
        for (int fe = 0; fe < 2; ++fe) {
          float x = acc2[fij][fe][r] + partf[eg * 1056 + (fij * 16 + quad * 4 + r) * 33 + fe * 16 + mlo] + bv[fe];
          v[fij][fe][r] = x * gv[fe];
          t += x * x;
        }
        sq[fij][r] = t;
      }
    #pragma unroll
    for (int o = 1; o < 16; o <<= 1)
      #pragma unroll
      for (int fij = 0; fij < 2; ++fij)
        #pragma unroll
        for (int r = 0; r < 4; ++r) sq[fij][r] += __shfl_xor(sq[fij][r], o, 64);
    if (mlo == 0) {
      #pragma unroll
      for (int fij = 0; fij < 2; ++fij)
        #pragma unroll
        for (int r = 0; r < 4; ++r) red[(fij * 16 + quad * 4 + r) * 4 + eg] = sq[fij][r];
    }
  }
  __syncthreads();
  if (tid < 32) {
    float t = red[tid * 4] + red[tid * 4 + 1] + red[tid * 4 + 2] + red[tid * 4 + 3];
    sclp[tid] = rsqrtf(t * (1.f / 128.f) + EPS);
  }
  __syncthreads();
  if (kh == 0) {
    #pragma unroll
    for (int fij = 0; fij < 2; ++fij)
      #pragma unroll
      for (int r = 0; r < 4; ++r) {
        int ij = fij * 16 + quad * 4 + r;
        float sc = sclp[ij];
        int gi = ti * 8 + (ij >> 2), gj = tj * 4 + (ij & 3);
        #pragma unroll
        for (int fe = 0; fe < 2; ++fe)
          out[((size_t)gi * S + gj) * CZ + e0 + fe * 16 + mlo] = v[fij][fe][r] * sc;
      }
  }
}

// ---------------------------------------------------------------------------------------------------
extern "C" void kernel_launch(void* const* d_in, const int* in_sizes, int n_in,
                              void* d_out, int out_size, void* d_ws, size_t ws_size,
                              hipStream_t stream) {
  const float* m    = (const float*)d_in[0];
  const float* gin  = (const float*)d_in[1];
  const float* Wq   = (const float*)d_in[2];
  const float* bq   = (const float*)d_in[3];
  const float* Wk   = (const float*)d_in[4];
  const float* bk   = (const float*)d_in[5];
  const float* Wo   = (const float*)d_in[6];
  const float* bo   = (const float*)d_in[7];
  const float* gout = (const float*)d_in[8];

  char* ws = (char*)d_ws;
  unsigned short* qT    = (unsigned short*)(ws + OFF_QT);
  unsigned short* kT    = (unsigned short*)(ws + OFF_KT);
  unsigned short* WTg   = (unsigned short*)(ws + OFF_WT);
  unsigned short* WoTp  = (unsigned short*)(ws + OFF_WOT);
  float* out = (float*)d_out;

  hipLaunchKernelGGL(k0_prep, dim3(576), dim3(256), 0, stream, Wq, Wk, Wo, gin, WTg, WoTp);
  hipLaunchKernelGGL(k2_proj, dim3(96, 16), dim3(256), 0, stream, m, WTg, bq, bk, qT, kT);
  hipLaunchKernelGGL(k3_fused, dim3(4608), dim3(512), 0, stream, qT, kT, WoTp, bo, gout, out);
}